// Round 1
// baseline (225.081 us; speedup 1.0000x reference)
//
#include <hip/hip_runtime.h>
#include <math.h>

// DeepIRT forward. Dims from the reference:
#define B_   64
#define T_   256
#define M_   64
#define DK_  128
#define DV_  256
#define S_   128
#define NQR  201     // Eq rows  (q_data in [0,200])
#define NQAR 401     // Eqa rows (qa_data in [0,400])
#define NSR  2001    // Es rows  (s_data in [0,2000])

static __device__ __forceinline__ int imin(int a, int b){ return a < b ? a : b; }

// ---------------------------------------------------------------------------
// Role: corr_table[i][m] = softmax_m( Eq[i] . Km[m] ).  4 rows/block, 1 wave/row.
// ---------------------------------------------------------------------------
__device__ void corr_role(int blk, const float* __restrict__ Eq,
                          const float* __restrict__ Km, float* __restrict__ corr)
{
  __shared__ float eq[4][DK_];
  const int w = threadIdx.x >> 6, m = threadIdx.x & 63;
  const int i  = blk * 4 + w;
  const int ic = imin(i, NQR - 1);
  eq[w][m]      = Eq[ic * DK_ + m];
  eq[w][m + 64] = Eq[ic * DK_ + 64 + m];
  // each wave reads only its own eq[w] row -> no cross-wave barrier needed
  float acc = 0.f;
  const float4* kr = (const float4*)(Km + m * DK_);
  #pragma unroll 8
  for (int k4 = 0; k4 < DK_ / 4; ++k4) {
    float4 kv = kr[k4];
    acc = fmaf(eq[w][k4 * 4 + 0], kv.x, acc);
    acc = fmaf(eq[w][k4 * 4 + 1], kv.y, acc);
    acc = fmaf(eq[w][k4 * 4 + 2], kv.z, acc);
    acc = fmaf(eq[w][k4 * 4 + 3], kv.w, acc);
  }
  float mx = acc;
  #pragma unroll
  for (int off = 32; off; off >>= 1) mx = fmaxf(mx, __shfl_xor(mx, off, 64));
  float e = expf(acc - mx);
  float ssum = e;
  #pragma unroll
  for (int off = 32; off; off >>= 1) ssum += __shfl_xor(ssum, off, 64);
  if (i < NQR) corr[i * M_ + m] = e / ssum;
}

// ---------------------------------------------------------------------------
// Role: erase/add tables.  er[i][d] = Eqa[i].We[:,d] + be[d]; ad likewise with Wa/ba.
// 8 rows/block, thread = d.
// ---------------------------------------------------------------------------
__device__ void ea_role(int blk, const float* __restrict__ Eqa,
                        const float* __restrict__ We, const float* __restrict__ be,
                        const float* __restrict__ Wa, const float* __restrict__ ba,
                        float* __restrict__ ert, float* __restrict__ adt)
{
  __shared__ float a[8][DV_];
  const int d  = threadIdx.x;
  const int i0 = blk * 8;
  #pragma unroll
  for (int r = 0; r < 8; ++r) a[r][d] = Eqa[imin(i0 + r, NQAR - 1) * DV_ + d];
  __syncthreads();
  float er[8] = {0,0,0,0,0,0,0,0}, ad[8] = {0,0,0,0,0,0,0,0};
  for (int k = 0; k < DV_; ++k) {
    float we = We[k * DV_ + d];
    float wa = Wa[k * DV_ + d];
    #pragma unroll
    for (int r = 0; r < 8; ++r) {
      er[r] = fmaf(a[r][k], we, er[r]);
      ad[r] = fmaf(a[r][k], wa, ad[r]);
    }
  }
  const float beo = be[d], bao = ba[d];
  #pragma unroll
  for (int r = 0; r < 8; ++r) {
    int i = i0 + r;
    if (i < NQAR) { ert[i * DV_ + d] = er[r] + beo; adt[i * DV_ + d] = ad[r] + bao; }
  }
}

// ---------------------------------------------------------------------------
// Role: tanh-MLP scalar tables: out[i] = tanh(E[i]@W1 + b1) @ W2 + b2.
// 8 rows/block: thread = (rh in {0,1}, s in [0,128)); rh handles 4 rows.
// ---------------------------------------------------------------------------
__device__ void mlp_role(int blk, const float* __restrict__ E,
                         const float* __restrict__ W1, const float* __restrict__ b1,
                         const float* __restrict__ W2v, const float* __restrict__ b2,
                         float* __restrict__ outt, int nrows)
{
  __shared__ float e[8 * S_];
  __shared__ float red[8][2];
  const int tid = threadIdx.x;
  const int s = tid & 127, rh = tid >> 7;
  const int i0 = blk * 8;
  #pragma unroll
  for (int j = 0; j < 4; ++j) {
    int x = tid + j * 256;
    int row = imin(i0 + (x >> 7), nrows - 1);
    e[x] = E[row * DK_ + (x & 127)];
  }
  __syncthreads();
  float acc[4] = {0,0,0,0};
  const float* eb = e + rh * 4 * 128;
  for (int k = 0; k < DK_; ++k) {
    float wv = W1[k * S_ + s];
    #pragma unroll
    for (int r = 0; r < 4; ++r) acc[r] = fmaf(eb[r * 128 + k], wv, acc[r]);
  }
  const float b1s = b1[s], w2s = W2v[s];
  float p[4];
  #pragma unroll
  for (int r = 0; r < 4; ++r) p[r] = tanhf(acc[r] + b1s) * w2s;
  #pragma unroll
  for (int off = 32; off; off >>= 1) {
    #pragma unroll
    for (int r = 0; r < 4; ++r) p[r] += __shfl_xor(p[r], off, 64);
  }
  const int lane = tid & 63;
  const int half = s >> 6;
  if (lane == 0) {
    #pragma unroll
    for (int r = 0; r < 4; ++r) red[rh * 4 + r][half] = p[r];
  }
  __syncthreads();
  if (tid < 8) {
    int i = i0 + tid;
    if (i < nrows) outt[i] = red[tid][0] + red[tid][1] + b2[0];
  }
}

// ---------------------------------------------------------------------------
// Merged independent table kernels (one launch, block-range dispatch).
// ---------------------------------------------------------------------------
#define NB_CORR 51
#define NB_EA   51
#define NB_QD   26
#define NB_SD   251
#define NB_TOT  (NB_CORR + NB_EA + NB_QD + NB_SD)

__global__ __launch_bounds__(256) void tables_kernel(
    const float* Eq, const float* Km, float* corr_t,
    const float* Eqa, const float* We, const float* be,
    const float* Wa, const float* ba, float* er_t, float* ad_t,
    const float* Wqd1, const float* bqd1, const float* Wqd, const float* bqd, float* qd_t,
    const float* Es, const float* Wsd1, const float* bsd1, const float* Wsd, const float* bsd, float* sd_t)
{
  int blk = blockIdx.x;
  if (blk < NB_CORR) { corr_role(blk, Eq, Km, corr_t); return; }
  blk -= NB_CORR;
  if (blk < NB_EA)   { ea_role(blk, Eqa, We, be, Wa, ba, er_t, ad_t); return; }
  blk -= NB_EA;
  if (blk < NB_QD)   { mlp_role(blk, Eq, Wqd1, bqd1, Wqd, bqd, qd_t, NQR); return; }
  blk -= NB_QD;
  mlp_role(blk, Es, Wsd1, bsd1, Wsd, bsd, sd_t, NSR);
}

// ---------------------------------------------------------------------------
// w2_table[i][d] = sum_m corr[i][m] * Wsa[d][m];  csb_table[i] = corr[i].bsa
// (sa = read . w2_table[q] + csb_table[q] — eliminates per-step read@Wsa)
// ---------------------------------------------------------------------------
__global__ __launch_bounds__(256) void w2_kernel(
    const float* __restrict__ corr_t, const float* __restrict__ Wsa,
    const float* __restrict__ bsa, float* __restrict__ w2_t, float* __restrict__ csb_t)
{
  __shared__ float cw[M_];
  const int i = blockIdx.x;
  const int tid = threadIdx.x;
  if (tid < M_) cw[tid] = corr_t[i * M_ + tid];
  __syncthreads();
  const float4* wr = (const float4*)(Wsa + tid * M_);
  float acc = 0.f;
  #pragma unroll 4
  for (int m4 = 0; m4 < M_ / 4; ++m4) {
    float4 wv = wr[m4];
    acc = fmaf(cw[m4 * 4 + 0], wv.x, acc);
    acc = fmaf(cw[m4 * 4 + 1], wv.y, acc);
    acc = fmaf(cw[m4 * 4 + 2], wv.z, acc);
    acc = fmaf(cw[m4 * 4 + 3], wv.w, acc);
  }
  w2_t[i * DV_ + tid] = acc;
  if (tid < 64) {
    float pv = cw[tid] * bsa[tid];
    #pragma unroll
    for (int off = 32; off; off >>= 1) pv += __shfl_xor(pv, off, 64);
    if (tid == 0) csb_t[i] = pv;
  }
}

// ---------------------------------------------------------------------------
// The sequential scan. Grid (8, B): x = dq*2 + mh. 256 threads = 4 waves.
// Wave owns Mv[m0..m0+7][dq*64..dq*64+63] (8 regs/lane), fully independent:
// no barrier inside the 256-step loop. Emits per-step partial
// p = sum_{d in chunk} (sum_{m in group} cw[m]*Mv[m][d]) * w2[d]  (shuffle-reduced).
// ---------------------------------------------------------------------------
__global__ __launch_bounds__(256) void scan_kernel(
    const int* __restrict__ q_data, const int* __restrict__ qa_data,
    const float* __restrict__ corr_t, const float* __restrict__ er_t,
    const float* __restrict__ ad_t, const float* __restrict__ w2_t,
    const float* __restrict__ Vm, float* __restrict__ sa_part)
{
  const int b  = blockIdx.y;
  const int xx = blockIdx.x;     // 0..7
  const int dq = xx >> 1;        // d chunk 0..3
  const int mh = xx & 1;
  const int tid = threadIdx.x;
  const int dl  = tid & 63;
  const int w   = tid >> 6;      // wave in block
  const int mg  = mh * 4 + w;    // m group 0..7
  const int m0  = mg * 8;
  const int d   = dq * 64 + dl;

  __shared__ int qs[T_];
  __shared__ int qas[T_];
  qs[tid]  = q_data[b * T_ + tid];
  qas[tid] = qa_data[b * T_ + tid];

  float Mv[8];
  #pragma unroll
  for (int j = 0; j < 8; ++j) Mv[j] = Vm[(m0 + j) * DV_ + d];
  __syncthreads();

  // step-0 operands
  int q = qs[0], qa = qas[0];
  float4 ca = *(const float4*)(corr_t + q * M_ + m0);
  float4 cb = *(const float4*)(corr_t + q * M_ + m0 + 4);
  float er = er_t[qa * DV_ + d];
  float ad = ad_t[qa * DV_ + d];
  float w2 = w2_t[q * DV_ + d];

  for (int t = 0; t < T_; ++t) {
    // prefetch next step's tables (t=255 reloads step 0; harmless)
    const int tn = (t + 1) & (T_ - 1);
    const int qn = qs[tn], qan = qas[tn];
    float4 can = *(const float4*)(corr_t + qn * M_ + m0);
    float4 cbn = *(const float4*)(corr_t + qn * M_ + m0 + 4);
    float ern = er_t[qan * DV_ + d];
    float adn = ad_t[qan * DV_ + d];
    float w2n = w2_t[qn * DV_ + d];

    const float cw[8] = {ca.x, ca.y, ca.z, ca.w, cb.x, cb.y, cb.z, cb.w};
    float r0 = 0.f, r1 = 0.f;
    #pragma unroll
    for (int j = 0; j < 8; ++j) {
      const float c = cw[j];
      if (j & 1) r1 = fmaf(c, Mv[j], r1);      // read partial uses PRE-update Mv
      else       r0 = fmaf(c, Mv[j], r0);
      const float tmp = fmaf(-er, Mv[j], ad);  // ad - er*Mv
      Mv[j] = fmaf(c, tmp, Mv[j]);             // Mv*(1-c*er) + c*ad
    }
    float p = (r0 + r1) * w2;
    #pragma unroll
    for (int off = 32; off; off >>= 1) p += __shfl_xor(p, off, 64);
    if (dl == 0) sa_part[(b * T_ + t) * 32 + dq * 8 + mg] = p;

    ca = can; cb = cbn; er = ern; ad = adn; w2 = w2n;
  }
}

// ---------------------------------------------------------------------------
// out[b,t] = sigmoid( 3*(sum of 32 sa partials + csb[q]) - qd[q] - sd[s] )
// ---------------------------------------------------------------------------
__global__ __launch_bounds__(256) void final_kernel(
    const int* __restrict__ q_data, const int* __restrict__ s_data,
    const float* __restrict__ sa_part, const float* __restrict__ csb_t,
    const float* __restrict__ qd_t, const float* __restrict__ sd_t,
    float* __restrict__ out)
{
  const int bt = blockIdx.x * 256 + threadIdx.x;
  const float4* sp = (const float4*)(sa_part + bt * 32);
  float s = 0.f;
  #pragma unroll
  for (int j = 0; j < 8; ++j) { float4 v = sp[j]; s += (v.x + v.y) + (v.z + v.w); }
  const int q  = q_data[bt];
  const int si = s_data[bt];
  const float sa = s + csb_t[q];
  const float z = 3.f * sa - qd_t[q] - sd_t[si];
  out[bt] = 1.f / (1.f + expf(-z));
}

// ---------------------------------------------------------------------------
extern "C" void kernel_launch(void* const* d_in, const int* in_sizes, int n_in,
                              void* d_out, int out_size, void* d_ws, size_t ws_size,
                              hipStream_t stream)
{
  const int*   q_data = (const int*)d_in[0];
  const int*   qa_data= (const int*)d_in[1];
  const int*   s_data = (const int*)d_in[2];
  const float* Km     = (const float*)d_in[3];
  const float* Vm     = (const float*)d_in[4];
  const float* Eq     = (const float*)d_in[5];
  const float* Eqa    = (const float*)d_in[6];
  const float* Es     = (const float*)d_in[7];
  const float* We     = (const float*)d_in[8];
  const float* be     = (const float*)d_in[9];
  const float* Wa     = (const float*)d_in[10];
  const float* ba     = (const float*)d_in[11];
  const float* Wsa    = (const float*)d_in[12];
  const float* bsa    = (const float*)d_in[13];
  const float* Wqd1   = (const float*)d_in[14];
  const float* bqd1   = (const float*)d_in[15];
  const float* Wqd    = (const float*)d_in[16];
  const float* bqd    = (const float*)d_in[17];
  const float* Wsd1   = (const float*)d_in[18];
  const float* bsd1   = (const float*)d_in[19];
  const float* Wsd    = (const float*)d_in[20];
  const float* bsd    = (const float*)d_in[21];
  float* out = (float*)d_out;

  // workspace layout (floats, 16B-aligned chunks); total ~3.2 MB
  float* wsf    = (float*)d_ws;
  float* corr_t = wsf;                       // 201*64   = 12864
  float* w2_t   = corr_t + NQR * M_;         // 201*256  = 51456
  float* csb_t  = w2_t + NQR * DV_;          // 201 -> pad 204
  float* er_t   = csb_t + 204;               // 401*256  = 102656
  float* ad_t   = er_t + NQAR * DV_;         // 102656
  float* qd_t   = ad_t + NQAR * DV_;         // 201 -> pad 204
  float* sd_t   = qd_t + 204;                // 2001 -> pad 2004
  float* sa_p   = sd_t + 2004;               // 64*256*32 = 524288

  tables_kernel<<<NB_TOT, 256, 0, stream>>>(
      Eq, Km, corr_t, Eqa, We, be, Wa, ba, er_t, ad_t,
      Wqd1, bqd1, Wqd, bqd, qd_t,
      Es, Wsd1, bsd1, Wsd, bsd, sd_t);
  w2_kernel<<<NQR, 256, 0, stream>>>(corr_t, Wsa, bsa, w2_t, csb_t);
  scan_kernel<<<dim3(8, B_), 256, 0, stream>>>(q_data, qa_data, corr_t, er_t, ad_t, w2_t, Vm, sa_p);
  final_kernel<<<B_, 256, 0, stream>>>(q_data, s_data, sa_p, csb_t, qd_t, sd_t, out);
}

// Round 2
// 188.547 us; speedup vs baseline: 1.1938x; 1.1938x over previous
//
#include <hip/hip_runtime.h>
#include <math.h>

// DeepIRT forward. Dims from the reference:
#define B_   64
#define T_   256
#define M_   64
#define DK_  128
#define DV_  256
#define S_   128
#define NQR  201     // Eq rows  (q_data in [0,200])
#define NQAR 401     // Eqa rows (qa_data in [0,400])
#define NSR  2001    // Es rows  (s_data in [0,2000])

static __device__ __forceinline__ int imin(int a, int b){ return a < b ? a : b; }

static __device__ __forceinline__ float fast_tanh(float x){
  float e = __expf(2.f * x);
  return 1.f - 2.f / (e + 1.f);
}

// ---------------------------------------------------------------------------
// DPP wave64 sum: 6 dependent VALU adds, result in lane 63. No LDS pipe.
// row_shr:1/2/4/8 then row_bcast:15 (rows 1,3) and row_bcast:31 (rows 2,3).
// ---------------------------------------------------------------------------
template<int CTRL, int RM>
static __device__ __forceinline__ float dppadd(float x) {
  return x + __int_as_float(
      __builtin_amdgcn_update_dpp(0, __float_as_int(x), CTRL, RM, 0xf, true));
}
static __device__ __forceinline__ float wave_sum_lane63(float x) {
  x = dppadd<0x111, 0xf>(x);  // row_shr:1
  x = dppadd<0x112, 0xf>(x);  // row_shr:2
  x = dppadd<0x114, 0xf>(x);  // row_shr:4
  x = dppadd<0x118, 0xf>(x);  // row_shr:8  -> lane15/31/47/63 hold row sums
  x = dppadd<0x142, 0xa>(x);  // row_bcast:15 -> lane31=rows0-1, lane63=rows2-3
  x = dppadd<0x143, 0xc>(x);  // row_bcast:31 -> lane63=all 64
  return x;
}

// ---------------------------------------------------------------------------
// Role: corr row + fused w2/csb rows.  4 rows/block, 1 wave/row.
//   corr[i][m] = softmax_m( Eq[i] . Km[m] )
//   w2[i][d]   = sum_m corr[i][m] * Wsa[d][m]
//   csb[i]     = corr[i] . bsa
// ---------------------------------------------------------------------------
__device__ void corr_role(int blk, const float* __restrict__ Eq,
                          const float* __restrict__ Km,
                          const float* __restrict__ Wsa,
                          const float* __restrict__ bsa,
                          float* __restrict__ corr,
                          float* __restrict__ w2_t,
                          float* __restrict__ csb_t)
{
  __shared__ float eq[4][DK_];
  __shared__ float cwb[4][M_];
  const int w = threadIdx.x >> 6, m = threadIdx.x & 63;
  const int i  = blk * 4 + w;
  const int ic = imin(i, NQR - 1);
  eq[w][m]      = Eq[ic * DK_ + m];
  eq[w][m + 64] = Eq[ic * DK_ + 64 + m];
  // each wave reads only its own eq row -> no cross-wave barrier needed
  float acc = 0.f;
  const float4* kr = (const float4*)(Km + m * DK_);
  #pragma unroll 8
  for (int k4 = 0; k4 < DK_ / 4; ++k4) {
    float4 kv = kr[k4];
    acc = fmaf(eq[w][k4 * 4 + 0], kv.x, acc);
    acc = fmaf(eq[w][k4 * 4 + 1], kv.y, acc);
    acc = fmaf(eq[w][k4 * 4 + 2], kv.z, acc);
    acc = fmaf(eq[w][k4 * 4 + 3], kv.w, acc);
  }
  float mx = acc;
  #pragma unroll
  for (int off = 32; off; off >>= 1) mx = fmaxf(mx, __shfl_xor(mx, off, 64));
  float e = __expf(acc - mx);
  float ssum = e;
  #pragma unroll
  for (int off = 32; off; off >>= 1) ssum += __shfl_xor(ssum, off, 64);
  const float cw = e / ssum;
  if (i < NQR) corr[i * M_ + m] = cw;
  cwb[w][m] = cw;

  // csb: one DPP reduce
  float pv = wave_sum_lane63(cw * bsa[m]);
  if (m == 63 && i < NQR) csb_t[i] = pv;

  // w2 row: lane m computes d = r*64 + m for r=0..3 (coalesced stores)
  float aw[4] = {0,0,0,0};
  for (int mm = 0; mm < M_; ++mm) {
    const float c = cwb[w][mm];   // same-wave LDS broadcast
    #pragma unroll
    for (int r = 0; r < 4; ++r)
      aw[r] = fmaf(c, Wsa[(r * 64 + m) * M_ + mm], aw[r]);
  }
  if (i < NQR) {
    #pragma unroll
    for (int r = 0; r < 4; ++r) w2_t[i * DV_ + r * 64 + m] = aw[r];
  }
}

// ---------------------------------------------------------------------------
// Role: erase/add tables.  er[i][d] = Eqa[i].We[:,d] + be[d]; ad with Wa/ba.
// 8 rows/block, thread = d.
// ---------------------------------------------------------------------------
__device__ void ea_role(int blk, const float* __restrict__ Eqa,
                        const float* __restrict__ We, const float* __restrict__ be,
                        const float* __restrict__ Wa, const float* __restrict__ ba,
                        float* __restrict__ ert, float* __restrict__ adt)
{
  __shared__ float a[8][DV_];
  const int d  = threadIdx.x;
  const int i0 = blk * 8;
  #pragma unroll
  for (int r = 0; r < 8; ++r) a[r][d] = Eqa[imin(i0 + r, NQAR - 1) * DV_ + d];
  __syncthreads();
  float er[8] = {0,0,0,0,0,0,0,0}, ad[8] = {0,0,0,0,0,0,0,0};
  for (int k = 0; k < DV_; ++k) {
    float we = We[k * DV_ + d];
    float wa = Wa[k * DV_ + d];
    #pragma unroll
    for (int r = 0; r < 8; ++r) {
      er[r] = fmaf(a[r][k], we, er[r]);
      ad[r] = fmaf(a[r][k], wa, ad[r]);
    }
  }
  const float beo = be[d], bao = ba[d];
  #pragma unroll
  for (int r = 0; r < 8; ++r) {
    int i = i0 + r;
    if (i < NQAR) { ert[i * DV_ + d] = er[r] + beo; adt[i * DV_ + d] = ad[r] + bao; }
  }
}

// ---------------------------------------------------------------------------
// Role: tanh-MLP scalar tables: out[i] = tanh(E[i]@W1 + b1) @ W2 + b2.
// 8 rows/block: thread = (rh in {0,1}, s in [0,128)); rh handles 4 rows.
// ---------------------------------------------------------------------------
__device__ void mlp_role(int blk, const float* __restrict__ E,
                         const float* __restrict__ W1, const float* __restrict__ b1,
                         const float* __restrict__ W2v, const float* __restrict__ b2,
                         float* __restrict__ outt, int nrows)
{
  __shared__ float e[8 * S_];
  __shared__ float red[8][2];
  const int tid = threadIdx.x;
  const int s = tid & 127, rh = tid >> 7;
  const int i0 = blk * 8;
  #pragma unroll
  for (int j = 0; j < 4; ++j) {
    int x = tid + j * 256;
    int row = imin(i0 + (x >> 7), nrows - 1);
    e[x] = E[row * DK_ + (x & 127)];
  }
  __syncthreads();
  float acc[4] = {0,0,0,0};
  const float* eb = e + rh * 4 * 128;
  for (int k = 0; k < DK_; ++k) {
    float wv = W1[k * S_ + s];
    #pragma unroll
    for (int r = 0; r < 4; ++r) acc[r] = fmaf(eb[r * 128 + k], wv, acc[r]);
  }
  const float b1s = b1[s], w2s = W2v[s];
  float p[4];
  #pragma unroll
  for (int r = 0; r < 4; ++r) p[r] = fast_tanh(acc[r] + b1s) * w2s;
  #pragma unroll
  for (int r = 0; r < 4; ++r) p[r] = wave_sum_lane63(p[r]);
  const int lane = tid & 63;
  const int half = s >> 6;
  if (lane == 63) {
    #pragma unroll
    for (int r = 0; r < 4; ++r) red[rh * 4 + r][half] = p[r];
  }
  __syncthreads();
  if (tid < 8) {
    int i = i0 + tid;
    if (i < nrows) outt[i] = red[tid][0] + red[tid][1] + b2[0];
  }
}

// ---------------------------------------------------------------------------
// Merged independent table kernels (one launch, block-range dispatch).
// ---------------------------------------------------------------------------
#define NB_CORR 51
#define NB_EA   51
#define NB_QD   26
#define NB_SD   251
#define NB_TOT  (NB_CORR + NB_EA + NB_QD + NB_SD)

__global__ __launch_bounds__(256) void tables_kernel(
    const float* Eq, const float* Km, const float* Wsa, const float* bsa,
    float* corr_t, float* w2_t, float* csb_t,
    const float* Eqa, const float* We, const float* be,
    const float* Wa, const float* ba, float* er_t, float* ad_t,
    const float* Wqd1, const float* bqd1, const float* Wqd, const float* bqd, float* qd_t,
    const float* Es, const float* Wsd1, const float* bsd1, const float* Wsd, const float* bsd, float* sd_t)
{
  int blk = blockIdx.x;
  if (blk < NB_CORR) { corr_role(blk, Eq, Km, Wsa, bsa, corr_t, w2_t, csb_t); return; }
  blk -= NB_CORR;
  if (blk < NB_EA)   { ea_role(blk, Eqa, We, be, Wa, ba, er_t, ad_t); return; }
  blk -= NB_EA;
  if (blk < NB_QD)   { mlp_role(blk, Eq, Wqd1, bqd1, Wqd, bqd, qd_t, NQR); return; }
  blk -= NB_QD;
  mlp_role(blk, Es, Wsd1, bsd1, Wsd, bsd, sd_t, NSR);
}

// ---------------------------------------------------------------------------
// The sequential scan. Grid (8, B): x = dq*2 + mh. 256 threads = 4 waves.
// Wave owns Mv[m0..m0+7][dq*64..dq*64+63] (8 regs/lane), fully independent:
// no barrier inside the 256-step loop. Per-step partial reduced via DPP
// (VALU-only, ~40 cyc) instead of ds_swizzle shuffles (~700 cyc chain).
// ---------------------------------------------------------------------------
struct Ops { float4 ca, cb; float er, ad, w2; };

static __device__ __forceinline__ Ops load_ops(
    int q, int qa, int m0, int d,
    const float* __restrict__ corr_t, const float* __restrict__ er_t,
    const float* __restrict__ ad_t, const float* __restrict__ w2_t)
{
  Ops o;
  o.ca = *(const float4*)(corr_t + q * M_ + m0);      // wave-uniform -> s_load
  o.cb = *(const float4*)(corr_t + q * M_ + m0 + 4);
  o.er = er_t[qa * DV_ + d];
  o.ad = ad_t[qa * DV_ + d];
  o.w2 = w2_t[q * DV_ + d];
  return o;
}

static __device__ __forceinline__ void scan_step(
    float (&Mv)[8], const Ops& o, float* __restrict__ dst, int dl)
{
  const float cw[8] = {o.ca.x, o.ca.y, o.ca.z, o.ca.w, o.cb.x, o.cb.y, o.cb.z, o.cb.w};
  float r0 = 0.f, r1 = 0.f;
  #pragma unroll
  for (int j = 0; j < 8; ++j) {
    const float c = cw[j];
    if (j & 1) r1 = fmaf(c, Mv[j], r1);      // read partial uses PRE-update Mv
    else       r0 = fmaf(c, Mv[j], r0);
    const float tmp = fmaf(-o.er, Mv[j], o.ad);  // ad - er*Mv
    Mv[j] = fmaf(c, tmp, Mv[j]);                 // Mv*(1-c*er) + c*ad
  }
  float p = wave_sum_lane63((r0 + r1) * o.w2);
  if (dl == 63) *dst = p;
}

__global__ __launch_bounds__(256) void scan_kernel(
    const int* __restrict__ q_data, const int* __restrict__ qa_data,
    const float* __restrict__ corr_t, const float* __restrict__ er_t,
    const float* __restrict__ ad_t, const float* __restrict__ w2_t,
    const float* __restrict__ Vm, float* __restrict__ sa_part)
{
  const int b  = blockIdx.y;
  const int xx = blockIdx.x;     // 0..7
  const int dq = xx >> 1;        // d chunk 0..3
  const int mh = xx & 1;
  const int tid = threadIdx.x;
  const int dl  = tid & 63;
  const int w   = tid >> 6;      // wave in block
  const int mg  = mh * 4 + w;    // m group 0..7
  const int m0  = __builtin_amdgcn_readfirstlane(mg * 8);  // force SGPR
  const int d   = dq * 64 + dl;

  __shared__ int qs[T_];
  __shared__ int qas[T_];
  qs[tid]  = q_data[b * T_ + tid];
  qas[tid] = qa_data[b * T_ + tid];

  float Mv[8];
  #pragma unroll
  for (int j = 0; j < 8; ++j) Mv[j] = Vm[(m0 + j) * DV_ + d];
  __syncthreads();

  float* base = sa_part + (b * T_) * 32 + dq * 8 + mg;

  // distance-2 software pipeline: operands for t and t+1 in flight
  int q0 = __builtin_amdgcn_readfirstlane(qs[0]);
  int a0 = __builtin_amdgcn_readfirstlane(qas[0]);
  int q1 = __builtin_amdgcn_readfirstlane(qs[1]);
  int a1 = __builtin_amdgcn_readfirstlane(qas[1]);
  Ops o0 = load_ops(q0, a0, m0, d, corr_t, er_t, ad_t, w2_t);
  Ops o1 = load_ops(q1, a1, m0, d, corr_t, er_t, ad_t, w2_t);

  for (int t = 0; t < T_; t += 2) {
    const int t2 = (t + 2) & (T_ - 1), t3 = (t + 3) & (T_ - 1);
    int q2 = __builtin_amdgcn_readfirstlane(qs[t2]);
    int a2 = __builtin_amdgcn_readfirstlane(qas[t2]);
    Ops o2 = load_ops(q2, a2, m0, d, corr_t, er_t, ad_t, w2_t);
    int q3 = __builtin_amdgcn_readfirstlane(qs[t3]);
    int a3 = __builtin_amdgcn_readfirstlane(qas[t3]);
    Ops o3 = load_ops(q3, a3, m0, d, corr_t, er_t, ad_t, w2_t);

    scan_step(Mv, o0, base + t * 32, dl);
    scan_step(Mv, o1, base + (t + 1) * 32, dl);
    o0 = o2; o1 = o3;
  }
}

// ---------------------------------------------------------------------------
// out[b,t] = sigmoid( 3*(sum of 32 sa partials + csb[q]) - qd[q] - sd[s] )
// ---------------------------------------------------------------------------
__global__ __launch_bounds__(256) void final_kernel(
    const int* __restrict__ q_data, const int* __restrict__ s_data,
    const float* __restrict__ sa_part, const float* __restrict__ csb_t,
    const float* __restrict__ qd_t, const float* __restrict__ sd_t,
    float* __restrict__ out)
{
  const int bt = blockIdx.x * 256 + threadIdx.x;
  const float4* sp = (const float4*)(sa_part + bt * 32);
  float s = 0.f;
  #pragma unroll
  for (int j = 0; j < 8; ++j) { float4 v = sp[j]; s += (v.x + v.y) + (v.z + v.w); }
  const int q  = q_data[bt];
  const int si = s_data[bt];
  const float sa = s + csb_t[q];
  const float z = 3.f * sa - qd_t[q] - sd_t[si];
  out[bt] = 1.f / (1.f + __expf(-z));
}

// ---------------------------------------------------------------------------
extern "C" void kernel_launch(void* const* d_in, const int* in_sizes, int n_in,
                              void* d_out, int out_size, void* d_ws, size_t ws_size,
                              hipStream_t stream)
{
  const int*   q_data = (const int*)d_in[0];
  const int*   qa_data= (const int*)d_in[1];
  const int*   s_data = (const int*)d_in[2];
  const float* Km     = (const float*)d_in[3];
  const float* Vm     = (const float*)d_in[4];
  const float* Eq     = (const float*)d_in[5];
  const float* Eqa    = (const float*)d_in[6];
  const float* Es     = (const float*)d_in[7];
  const float* We     = (const float*)d_in[8];
  const float* be     = (const float*)d_in[9];
  const float* Wa     = (const float*)d_in[10];
  const float* ba     = (const float*)d_in[11];
  const float* Wsa    = (const float*)d_in[12];
  const float* bsa    = (const float*)d_in[13];
  const float* Wqd1   = (const float*)d_in[14];
  const float* bqd1   = (const float*)d_in[15];
  const float* Wqd    = (const float*)d_in[16];
  const float* bqd    = (const float*)d_in[17];
  const float* Wsd1   = (const float*)d_in[18];
  const float* bsd1   = (const float*)d_in[19];
  const float* Wsd    = (const float*)d_in[20];
  const float* bsd    = (const float*)d_in[21];
  float* out = (float*)d_out;

  // workspace layout (floats, 16B-aligned chunks); total ~3.2 MB
  float* wsf    = (float*)d_ws;
  float* corr_t = wsf;                       // 201*64   = 12864
  float* w2_t   = corr_t + NQR * M_;         // 201*256  = 51456
  float* csb_t  = w2_t + NQR * DV_;          // 201 -> pad 204
  float* er_t   = csb_t + 204;               // 401*256  = 102656
  float* ad_t   = er_t + NQAR * DV_;         // 102656
  float* qd_t   = ad_t + NQAR * DV_;         // 201 -> pad 204
  float* sd_t   = qd_t + 204;                // 2001 -> pad 2004
  float* sa_p   = sd_t + 2004;               // 64*256*32 = 524288

  tables_kernel<<<NB_TOT, 256, 0, stream>>>(
      Eq, Km, Wsa, bsa, corr_t, w2_t, csb_t,
      Eqa, We, be, Wa, ba, er_t, ad_t,
      Wqd1, bqd1, Wqd, bqd, qd_t,
      Es, Wsd1, bsd1, Wsd, bsd, sd_t);
  scan_kernel<<<dim3(8, B_), 256, 0, stream>>>(q_data, qa_data, corr_t, er_t, ad_t, w2_t, Vm, sa_p);
  final_kernel<<<B_, 256, 0, stream>>>(q_data, s_data, sa_p, csb_t, qd_t, sd_t, out);
}